// Round 1
// 193.133 us; speedup vs baseline: 1.0049x; 1.0049x over previous
//
#include <hip/hip_runtime.h>

#define RR 12
#define LL 1728
#define CC 768
#define HEADS 12
#define HD 64
#define BATCH 4

typedef __attribute__((ext_vector_type(8))) short bf8;   // 8 x bf16
typedef __attribute__((ext_vector_type(4))) float f4;    // 4 x fp32

__device__ inline unsigned short f2bf(float x) {         // RNE-ish
  unsigned int u = __float_as_uint(x);
  return (unsigned short)((u + 0x7FFFu + ((u >> 16) & 1u)) >> 16);
}
__device__ inline unsigned short f2bfr(float x) {        // round-half-up (cheap)
  return (unsigned short)((__float_as_uint(x) + 0x8000u) >> 16);
}

__device__ inline float fast_exp2(float x) {
#if __has_builtin(__builtin_amdgcn_exp2f)
  return __builtin_amdgcn_exp2f(x);
#else
  return exp2f(x);
#endif
}

// async 16B global->LDS (wave-uniform LDS base + lane*16)
__device__ inline void gld16(const unsigned short* g, unsigned short* l) {
  __builtin_amdgcn_global_load_lds((const __attribute__((address_space(1))) unsigned int*)g,
                                   (__attribute__((address_space(3))) unsigned int*)l, 16, 0, 0);
}

#define QSCALE 0.1803368801111244f  /* 0.125 * log2(e): folds softmax base-2 conversion in */

#define NLEPE 5184  /* 432 lines*xgroups x 3 ctiles x 4 batch */
#define NPREP 1296  /* 27 ltiles x 12 heads x 4 batch */

// ---------------- combined prep + lepe (block-uniform partition; 1 launch instead of 3) ------------
// blocks [0, NLEPE): LePE depthwise conv, writes conv+bias into out.
// blocks [NLEPE, NLEPE+NPREP): q,k -> bf16 (q pre-scaled by QSCALE); v -> vT[b][h][d][sigma(k)].
// NEW slot permutation (for swapped-QK in-register P):
//   sigma(k) with k = nt*16 + quad*4 + r  ->  slot = (nt>>1)*32 + quad*8 + (nt&1)*4 + r
// Applied to BOTH the in-register P fragments (attn) and vT (B-side) -> MFMA K-dim permutation,
// result-invariant. Under this sigma the S^T lane layout of mfma(K,Q) IS the PV B-fragment layout:
// P never touches LDS.
__global__ __launch_bounds__(256) void combined_kernel(const float* __restrict__ qkv,
                                                       const float* __restrict__ w,
                                                       const float* __restrict__ bias,
                                                       unsigned short* __restrict__ qb,
                                                       unsigned short* __restrict__ kb,
                                                       unsigned short* __restrict__ vT,
                                                       float* __restrict__ out) {
  __shared__ __align__(16) unsigned char smem[27648];  // union: lepe w-stage 27 KB / prep tl 8.3 KB
  const int bid = blockIdx.x;
  const int t = threadIdx.x;

  if (bid < NLEPE) {
    // ================= LePE =================
    const int xg = (bid % 3) * 4;            // x0 in {0,4,8}
    const int line = (bid / 3) % 144;        // z*12+y
    const int ct = (bid / 432) % 3;          // c-tile
    const int b = bid / 1296;
    const int z = line / RR;
    const int y = line % RR;
    const int c0 = ct * 256;
    const int c = c0 + t;
    float* w_lds = (float*)smem;

    // coalesced stage of w[c0*27 .. (c0+256)*27) as float4 (6912 floats)
    {
      const float* wsrc = w + (size_t)c0 * 27;
#pragma unroll
      for (int i = 0; i < 7; ++i) {
        const int idx = i * 256 + t;         // float4 index, 0..1727
        if (idx < 1728) *(float4*)&w_lds[idx * 4] = *(const float4*)&wsrc[idx * 4];
      }
    }
    __syncthreads();
    float wreg[27];
#pragma unroll
    for (int j = 0; j < 27; ++j) wreg[j] = w_lds[t * 27 + j];  // stride 27 ⊥ 32: 2-way, free

    const float* vb = qkv + ((size_t)(2 * BATCH + b)) * LL * CC + c;
    const float bv = bias[c];
    float acc[4] = {bv, bv, bv, bv};

#pragma unroll
    for (int dz = -1; dz <= 1; ++dz) {
#pragma unroll
      for (int dy = -1; dy <= 1; ++dy) {
        const int zz = z + dz, yy = y + dy;
        const bool lineok = ((unsigned)zz < RR) & ((unsigned)yy < RR);  // block-uniform
        const int base = (zz * RR + yy) * RR;
        float v6[6];                        // x-positions xg-1 .. xg+4, masked address-safe loads
#pragma unroll
        for (int p = 0; p < 6; ++p) {
          const int xx = xg - 1 + p;
          const bool ok = lineok & ((unsigned)xx < RR);
          const int lp = ok ? base + xx : 0;
          const float vv = vb[(size_t)lp * CC];
          v6[p] = ok ? vv : 0.f;
        }
        const int jb = ((dz + 1) * 3 + (dy + 1)) * 3;
        const float wL = wreg[jb], wC = wreg[jb + 1], wR = wreg[jb + 2];
#pragma unroll
        for (int i = 0; i < 4; ++i)
          acc[i] += wL * v6[i] + wC * v6[i + 1] + wR * v6[i + 2];
      }
    }
    const size_t obase = ((size_t)b * LL + line * RR + xg) * CC + c;
#pragma unroll
    for (int i = 0; i < 4; ++i) out[obase + (size_t)i * CC] = acc[i];

  } else {
    // ================= prep =================
    const int p = bid - NLEPE;
    const int lt = p % 27;
    const int h = (p / 27) % HEADS;
    const int b = p / (27 * HEADS);
    unsigned short* tl = (unsigned short*)smem;  // [d][l_local], stride 65

    // ---- q/k bf16 conversion for rows lt*64.., cols h*64.. ----
    {
      const int r0 = t >> 4;             // 0..15
      const int c4 = (t & 15) * 4;       // 0..60
#pragma unroll
      for (int pi = 0; pi < 4; ++pi) {
        const int row = lt * 64 + pi * 16 + r0;
        const size_t off = ((size_t)b * LL + row) * CC + h * HD + c4;
        const float4 qv = *(const float4*)(qkv + off);
        ushort4 oq;
        oq.x = f2bf(qv.x * QSCALE); oq.y = f2bf(qv.y * QSCALE);
        oq.z = f2bf(qv.z * QSCALE); oq.w = f2bf(qv.w * QSCALE);
        *(ushort4*)(qb + off) = oq;
        const float4 kv = *(const float4*)(qkv + (size_t)BATCH * LL * CC + off);
        ushort4 ok;
        ok.x = f2bf(kv.x); ok.y = f2bf(kv.y); ok.z = f2bf(kv.z); ok.w = f2bf(kv.w);
        *(ushort4*)(kb + off) = ok;
      }
    }

    // ---- vT with NEW slot permutation ----
    const float* vsrc = qkv + ((size_t)(2 * BATCH + b)) * LL * CC;
#pragma unroll
    for (int it = 0; it < 4; ++it) {
      const int idx = it * 256 + t;
      const int lrow = idx >> 4;
      const int c4 = (idx & 15) * 4;
      const float4 vv = *(const float4*)(vsrc + (size_t)(lt * 64 + lrow) * CC + h * HD + c4);
      tl[(c4 + 0) * 65 + lrow] = f2bf(vv.x);
      tl[(c4 + 1) * 65 + lrow] = f2bf(vv.y);
      tl[(c4 + 2) * 65 + lrow] = f2bf(vv.z);
      tl[(c4 + 3) * 65 + lrow] = f2bf(vv.w);
    }
    __syncthreads();
#pragma unroll
    for (int it = 0; it < 4; ++it) {
      const int idx = it * 256 + t;
      const int drow = idx >> 4;
      const int u = idx & 15;            // slot group: s4 = u*4
      const int s4 = u * 4;
      // slots s4..s4+3 hold physical kv rows kbase..kbase+3 (consecutive):
      //   kbase = ((u>>3)*2 + (u&1))*16 + ((u>>1)&3)*4
      const int kbase = (((u >> 3) * 2 + (u & 1)) << 4) + (((u >> 1) & 3) << 2);
      ushort4 o;
      o.x = tl[drow * 65 + kbase + 0];
      o.y = tl[drow * 65 + kbase + 1];
      o.z = tl[drow * 65 + kbase + 2];
      o.w = tl[drow * 65 + kbase + 3];
      *(ushort4*)(vT + (((size_t)(b * HEADS + h) * HD + drow) * LL) + lt * 64 + s4) = o;
    }
  }
}

// ---------------- Flash attention: dbuf DMA, exp2 softmax, deferred denominator --------------------
// Swapped QK^T (mfma(K,Q) -> S^T): lane (m,quad) holds S[k = nt*16+quad*4+r][q = m].
// With sigma(k) = (nt>>1)*32 + quad*8 + (nt&1)*4 + r, those 16 values are exactly the two
// B-fragments pf[ks] that PV (O^T = mfma(V^T, P^T)) consumes: P stays in registers, p_lds gone.
// LDS 41984 -> 32768 B => 5 blocks/CU (20 waves/CU) instead of 3 (12).
__global__ __launch_bounds__(256) void attn_kernel(const unsigned short* __restrict__ qb,
                                                   const unsigned short* __restrict__ kb,
                                                   const unsigned short* __restrict__ vT,
                                                   float* __restrict__ out) {
  __shared__ unsigned short k_lds[2][64 * 64];   // [buf][kv][d], XOR-swizzled chunks
  __shared__ unsigned short v_lds[2][64 * 64];   // [buf][d][slot], XOR-swizzled chunks

  const int qt = blockIdx.x;
  const int h = blockIdx.y;
  const int b = blockIdx.z;
  const int t = threadIdx.x;
  const int lane = t & 63;
  const int wave = t >> 6;
  const int m = lane & 15;
  const int quad = lane >> 4;

  // Q frags (pre-scaled bf16); B-operand layout: lane&15 = q col, quad*8 = d-slice within K=32
  bf8 qf[2];
  {
    const size_t qbase = ((size_t)(b * LL + qt * 64 + wave * 16 + m)) * CC + h * HD;
    qf[0] = *(const bf8*)(qb + qbase + quad * 8);
    qf[1] = *(const bf8*)(qb + qbase + 32 + quad * 8);
  }

  // DMA source offsets: chunk cidx=(j*4+wave)*64+lane; row=cidx>>3; src chunk=(cidx&7)^(row&7)
  int koff[2], voff[2], ldsb[2];
#pragma unroll
  for (int j = 0; j < 2; ++j) {
    const int cidx = (j * 4 + wave) * 64 + lane;
    const int row = cidx >> 3;
    const int sc = (cidx & 7) ^ (row & 7);
    koff[j] = row * CC + sc * 8;
    voff[j] = row * LL + sc * 8;
    ldsb[j] = (j * 4 + wave) * 512;
  }

  const unsigned short* kgb = kb + (size_t)b * LL * CC + h * HD;
  const unsigned short* vgb = vT + ((size_t)(b * HEADS + h) * HD) * LL;

  // prologue: tile 0 -> buf 0
  gld16(kgb + koff[0], &k_lds[0][ldsb[0]]);
  gld16(kgb + koff[1], &k_lds[0][ldsb[1]]);
  gld16(vgb + voff[0], &v_lds[0][ldsb[0]]);
  gld16(vgb + voff[1], &v_lds[0][ldsb[1]]);

  f4 o_acc[4] = {};
  float psum = 0.f;   // deferred softmax denominator (per-lane partial over this lane's 16 slots/tile)

  // body for one K-tile; CUR is compile-time so all LDS addresses fold to immediates
#define ATTN_BODY(KT, CUR)                                                              \
  {                                                                                     \
    __syncthreads(); /* implicit vmcnt(0): buf[CUR] ready; buf[CUR^1] free */           \
    if ((KT) < 26) {                                                                    \
      const size_t ko = (size_t)((KT) + 1) * 64 * CC;                                   \
      const int vo = ((KT) + 1) * 64;                                                   \
      gld16(kgb + ko + koff[0], &k_lds[(CUR) ^ 1][ldsb[0]]);                            \
      gld16(kgb + ko + koff[1], &k_lds[(CUR) ^ 1][ldsb[1]]);                            \
      gld16(vgb + vo + voff[0], &v_lds[(CUR) ^ 1][ldsb[0]]);                            \
      gld16(vgb + vo + voff[1], &v_lds[(CUR) ^ 1][ldsb[1]]);                            \
    }                                                                                   \
    f4 s_acc[4] = {};                                                                   \
    _Pragma("unroll")                                                                   \
    for (int nt = 0; nt < 4; ++nt) {                                                    \
      _Pragma("unroll")                                                                 \
      for (int ks = 0; ks < 2; ++ks) {                                                  \
        const int cc = ((ks * 4 + quad) ^ (m & 7)) * 8;                                 \
        const bf8 kf = *(const bf8*)&k_lds[CUR][(nt * 16 + m) * 64 + cc];               \
        s_acc[nt] = __builtin_amdgcn_mfma_f32_16x16x32_bf16(kf, qf[ks], s_acc[nt], 0, 0, 0); \
      }                                                                                 \
    }                                                                                   \
    bf8 pf[2];                                                                          \
    _Pragma("unroll")                                                                   \
    for (int ks = 0; ks < 2; ++ks) {                                                    \
      union { bf8 v; unsigned int w[4]; } pu;                                           \
      _Pragma("unroll")                                                                 \
      for (int bb = 0; bb < 2; ++bb) {                                                  \
        const int nt = ks * 2 + bb;                                                     \
        const float p0 = fast_exp2(s_acc[nt][0]);                                       \
        const float p1 = fast_exp2(s_acc[nt][1]);                                       \
        const float p2 = fast_exp2(s_acc[nt][2]);                                       \
        const float p3 = fast_exp2(s_acc[nt][3]);                                       \
        psum += (p0 + p1) + (p2 + p3);                                                  \
        pu.w[bb * 2 + 0] = (unsigned int)f2bfr(p0) | ((unsigned int)f2bfr(p1) << 16);   \
        pu.w[bb * 2 + 1] = (unsigned int)f2bfr(p2) | ((unsigned int)f2bfr(p3) << 16);   \
      }                                                                                 \
      pf[ks] = pu.v;                                                                    \
    }                                                                                   \
    _Pragma("unroll")                                                                   \
    for (int nt = 0; nt < 4; ++nt) {                                                    \
      _Pragma("unroll")                                                                 \
      for (int ks = 0; ks < 2; ++ks) {                                                  \
        const int cc = ((ks * 4 + quad) ^ (m & 7)) * 8;                                 \
        const bf8 vf = *(const bf8*)&v_lds[CUR][(nt * 16 + m) * 64 + cc];               \
        o_acc[nt] = __builtin_amdgcn_mfma_f32_16x16x32_bf16(vf, pf[ks], o_acc[nt], 0, 0, 0); \
      }                                                                                 \
    }                                                                                   \
  }

  for (int ktp = 0; ktp < 13; ++ktp) {
    const int kt0 = ktp * 2;
    ATTN_BODY(kt0, 0)
    ATTN_BODY(kt0 + 1, 1)
  }
  ATTN_BODY(26, 0)
#undef ATTN_BODY

  // ---- epilogue: denominator = sum over the 4 quads holding q=m, then out += O^T / l ----
  // o_acc[nt][r] = O[q = qt*64+wave*16+m][d = nt*16 + quad*4 + r]  -> float4 RMW per nt
  float s = psum;
  s += __shfl_xor(s, 16);
  s += __shfl_xor(s, 32);
  const float inv = 1.0f / s;
  const int rowq = qt * 64 + wave * 16 + m;
  float* op = out + ((size_t)b * LL + rowq) * CC + h * HD + quad * 4;
#pragma unroll
  for (int nt = 0; nt < 4; ++nt) {
    float4 o4 = *(float4*)&op[nt * 16];
    o4.x += o_acc[nt][0] * inv;
    o4.y += o_acc[nt][1] * inv;
    o4.z += o_acc[nt][2] * inv;
    o4.w += o_acc[nt][3] * inv;
    *(float4*)&op[nt * 16] = o4;
  }
}

extern "C" void kernel_launch(void* const* d_in, const int* in_sizes, int n_in,
                              void* d_out, int out_size, void* d_ws, size_t ws_size,
                              hipStream_t stream) {
  (void)in_sizes; (void)n_in; (void)ws_size; (void)out_size;
  const float* qkv = (const float*)d_in[0];
  const float* lepe_w = (const float*)d_in[1];
  const float* lepe_b = (const float*)d_in[2];
  float* out = (float*)d_out;

  const size_t NE = (size_t)BATCH * LL * CC;
  unsigned short* qb = (unsigned short*)d_ws;
  unsigned short* kb = qb + NE;
  unsigned short* vT = kb + NE;  // 3*NE*2 B ~ 31.9 MB of ws

  combined_kernel<<<dim3(NLEPE + NPREP), 256, 0, stream>>>(qkv, lepe_w, lepe_b, qb, kb, vT, out);
  attn_kernel<<<dim3(27, HEADS, BATCH), 256, 0, stream>>>(qb, kb, vT, out);
}

// Round 2
// 191.423 us; speedup vs baseline: 1.0139x; 1.0089x over previous
//
#include <hip/hip_runtime.h>

#define RR 12
#define LL 1728
#define CC 768
#define HEADS 12
#define HD 64
#define BATCH 4

typedef __attribute__((ext_vector_type(8))) short bf8;   // 8 x bf16
typedef __attribute__((ext_vector_type(4))) float f4;    // 4 x fp32

__device__ inline unsigned short f2bf(float x) {         // RNE-ish
  unsigned int u = __float_as_uint(x);
  return (unsigned short)((u + 0x7FFFu + ((u >> 16) & 1u)) >> 16);
}
__device__ inline unsigned short f2bfr(float x) {        // round-half-up (cheap)
  return (unsigned short)((__float_as_uint(x) + 0x8000u) >> 16);
}

__device__ inline float fast_exp2(float x) {
#if __has_builtin(__builtin_amdgcn_exp2f)
  return __builtin_amdgcn_exp2f(x);
#else
  return exp2f(x);
#endif
}

// async 16B global->LDS (wave-uniform LDS base + lane*16)
__device__ inline void gld16(const unsigned short* g, unsigned short* l) {
  __builtin_amdgcn_global_load_lds((const __attribute__((address_space(1))) unsigned int*)g,
                                   (__attribute__((address_space(3))) unsigned int*)l, 16, 0, 0);
}

#define QSCALE 0.1803368801111244f  /* 0.125 * log2(e): folds softmax base-2 conversion in */

#define NLEPE 5184  /* 432 lines*xgroups x 3 ctiles x 4 batch */
#define NPREP 1296  /* 27 ltiles x 12 heads x 4 batch */

// ---------------- combined prep + lepe (block-uniform partition; 1 launch instead of 3) ------------
// blocks [0, NLEPE): LePE depthwise conv, writes conv+bias into out.
// blocks [NLEPE, NLEPE+NPREP): q,k -> bf16 (q pre-scaled by QSCALE); v -> vT[b][h][d][sigma(k)].
// Slot permutation (for swapped-QK in-register P):
//   sigma(k) with k = nt*16 + quad*4 + r  ->  slot = (nt>>1)*32 + quad*8 + (nt&1)*4 + r
// Applied to BOTH the in-register P fragments (attn) and vT (B-side) -> MFMA K-dim permutation,
// result-invariant. Under this sigma the S^T lane layout of mfma(K,Q) IS the PV B-fragment layout:
// P never touches LDS.
__global__ __launch_bounds__(256) void combined_kernel(const float* __restrict__ qkv,
                                                       const float* __restrict__ w,
                                                       const float* __restrict__ bias,
                                                       unsigned short* __restrict__ qb,
                                                       unsigned short* __restrict__ kb,
                                                       unsigned short* __restrict__ vT,
                                                       float* __restrict__ out) {
  __shared__ __align__(16) unsigned char smem[27648];  // union: lepe w-stage 27 KB / prep tl 8.3 KB
  const int bid = blockIdx.x;
  const int t = threadIdx.x;

  if (bid < NLEPE) {
    // ================= LePE =================
    const int xg = (bid % 3) * 4;            // x0 in {0,4,8}
    const int line = (bid / 3) % 144;        // z*12+y
    const int ct = (bid / 432) % 3;          // c-tile
    const int b = bid / 1296;
    const int z = line / RR;
    const int y = line % RR;
    const int c0 = ct * 256;
    const int c = c0 + t;
    float* w_lds = (float*)smem;

    // coalesced stage of w[c0*27 .. (c0+256)*27) as float4 (6912 floats)
    {
      const float* wsrc = w + (size_t)c0 * 27;
#pragma unroll
      for (int i = 0; i < 7; ++i) {
        const int idx = i * 256 + t;         // float4 index, 0..1727
        if (idx < 1728) *(float4*)&w_lds[idx * 4] = *(const float4*)&wsrc[idx * 4];
      }
    }
    __syncthreads();
    float wreg[27];
#pragma unroll
    for (int j = 0; j < 27; ++j) wreg[j] = w_lds[t * 27 + j];  // stride 27 ⊥ 32: 2-way, free

    const float* vb = qkv + ((size_t)(2 * BATCH + b)) * LL * CC + c;
    const float bv = bias[c];
    float acc[4] = {bv, bv, bv, bv};

#pragma unroll
    for (int dz = -1; dz <= 1; ++dz) {
#pragma unroll
      for (int dy = -1; dy <= 1; ++dy) {
        const int zz = z + dz, yy = y + dy;
        const bool lineok = ((unsigned)zz < RR) & ((unsigned)yy < RR);  // block-uniform
        const int base = (zz * RR + yy) * RR;
        float v6[6];                        // x-positions xg-1 .. xg+4, masked address-safe loads
#pragma unroll
        for (int p = 0; p < 6; ++p) {
          const int xx = xg - 1 + p;
          const bool ok = lineok & ((unsigned)xx < RR);
          const int lp = ok ? base + xx : 0;
          const float vv = vb[(size_t)lp * CC];
          v6[p] = ok ? vv : 0.f;
        }
        const int jb = ((dz + 1) * 3 + (dy + 1)) * 3;
        const float wL = wreg[jb], wC = wreg[jb + 1], wR = wreg[jb + 2];
#pragma unroll
        for (int i = 0; i < 4; ++i)
          acc[i] += wL * v6[i] + wC * v6[i + 1] + wR * v6[i + 2];
      }
    }
    const size_t obase = ((size_t)b * LL + line * RR + xg) * CC + c;
#pragma unroll
    for (int i = 0; i < 4; ++i) out[obase + (size_t)i * CC] = acc[i];

  } else {
    // ================= prep =================
    const int p = bid - NLEPE;
    const int lt = p % 27;
    const int h = (p / 27) % HEADS;
    const int b = p / (27 * HEADS);
    unsigned short* tl = (unsigned short*)smem;  // [d][l_local], stride 65

    // ---- q/k bf16 conversion for rows lt*64.., cols h*64.. ----
    {
      const int r0 = t >> 4;             // 0..15
      const int c4 = (t & 15) * 4;       // 0..60
#pragma unroll
      for (int pi = 0; pi < 4; ++pi) {
        const int row = lt * 64 + pi * 16 + r0;
        const size_t off = ((size_t)b * LL + row) * CC + h * HD + c4;
        const float4 qv = *(const float4*)(qkv + off);
        ushort4 oq;
        oq.x = f2bf(qv.x * QSCALE); oq.y = f2bf(qv.y * QSCALE);
        oq.z = f2bf(qv.z * QSCALE); oq.w = f2bf(qv.w * QSCALE);
        *(ushort4*)(qb + off) = oq;
        const float4 kv = *(const float4*)(qkv + (size_t)BATCH * LL * CC + off);
        ushort4 ok;
        ok.x = f2bf(kv.x); ok.y = f2bf(kv.y); ok.z = f2bf(kv.z); ok.w = f2bf(kv.w);
        *(ushort4*)(kb + off) = ok;
      }
    }

    // ---- vT with slot permutation ----
    const float* vsrc = qkv + ((size_t)(2 * BATCH + b)) * LL * CC;
#pragma unroll
    for (int it = 0; it < 4; ++it) {
      const int idx = it * 256 + t;
      const int lrow = idx >> 4;
      const int c4 = (idx & 15) * 4;
      const float4 vv = *(const float4*)(vsrc + (size_t)(lt * 64 + lrow) * CC + h * HD + c4);
      tl[(c4 + 0) * 65 + lrow] = f2bf(vv.x);
      tl[(c4 + 1) * 65 + lrow] = f2bf(vv.y);
      tl[(c4 + 2) * 65 + lrow] = f2bf(vv.z);
      tl[(c4 + 3) * 65 + lrow] = f2bf(vv.w);
    }
    __syncthreads();
#pragma unroll
    for (int it = 0; it < 4; ++it) {
      const int idx = it * 256 + t;
      const int drow = idx >> 4;
      const int u = idx & 15;            // slot group: s4 = u*4
      const int s4 = u * 4;
      // slots s4..s4+3 hold physical kv rows kbase..kbase+3 (consecutive):
      //   kbase = ((u>>3)*2 + (u&1))*16 + ((u>>1)&3)*4
      const int kbase = (((u >> 3) * 2 + (u & 1)) << 4) + (((u >> 1) & 3) << 2);
      ushort4 o;
      o.x = tl[drow * 65 + kbase + 0];
      o.y = tl[drow * 65 + kbase + 1];
      o.z = tl[drow * 65 + kbase + 2];
      o.w = tl[drow * 65 + kbase + 3];
      *(ushort4*)(vT + (((size_t)(b * HEADS + h) * HD + drow) * LL) + lt * 64 + s4) = o;
    }
  }
}

// ---------------- Flash attention: Q=128/block, 2 q-subtiles per wave -----------------------------
// Swapped QK^T (mfma(K,Q) -> S^T): lane (m,quad) holds S[k][q=m]; sigma-permuted slots make the
// in-register exp2(S) fragments directly consumable as PV's B-operand (no P LDS round-trip).
// Each wave owns 32 q-rows (sub=0: rows wave*16+m, sub=1: +64). K/V fragments from LDS are shared
// across both subtiles: ds_read_b128 issue and K/V DMA staging per output are HALVED vs Q=64.
__global__ __launch_bounds__(256) void attn_kernel(const unsigned short* __restrict__ qb,
                                                   const unsigned short* __restrict__ kb,
                                                   const unsigned short* __restrict__ vT,
                                                   float* __restrict__ out) {
  __shared__ unsigned short k_lds[2][64 * 64];   // [buf][kv][d], XOR-swizzled chunks
  __shared__ unsigned short v_lds[2][64 * 64];   // [buf][d][slot], XOR-swizzled chunks

  const int qt = blockIdx.x;                     // 0..13 (qt 13 is a half tile)
  const int h = blockIdx.y;
  const int b = blockIdx.z;
  const int t = threadIdx.x;
  const int lane = t & 63;
  const int wave = t >> 6;
  const int m = lane & 15;
  const int quad = lane >> 4;

  // Q frags (pre-scaled bf16); B-operand layout: lane&15 = q col, quad*8 = d-slice within K=32
  bf8 qf[2][2];
#pragma unroll
  for (int sub = 0; sub < 2; ++sub) {
    int row = qt * 128 + sub * 64 + wave * 16 + m;
    row = row < LL ? row : LL - 1;               // clamp for the qt==13 half tile
    const size_t qbase = ((size_t)(b * LL + row)) * CC + h * HD;
    qf[sub][0] = *(const bf8*)(qb + qbase + quad * 8);
    qf[sub][1] = *(const bf8*)(qb + qbase + 32 + quad * 8);
  }

  // DMA source offsets: chunk cidx=(j*4+wave)*64+lane; row=cidx>>3; src chunk=(cidx&7)^(row&7)
  int koff[2], voff[2], ldsb[2];
#pragma unroll
  for (int j = 0; j < 2; ++j) {
    const int cidx = (j * 4 + wave) * 64 + lane;
    const int row = cidx >> 3;
    const int sc = (cidx & 7) ^ (row & 7);
    koff[j] = row * CC + sc * 8;
    voff[j] = row * LL + sc * 8;
    ldsb[j] = (j * 4 + wave) * 512;
  }

  const unsigned short* kgb = kb + (size_t)b * LL * CC + h * HD;
  const unsigned short* vgb = vT + ((size_t)(b * HEADS + h) * HD) * LL;

  // prologue: tile 0 -> buf 0
  gld16(kgb + koff[0], &k_lds[0][ldsb[0]]);
  gld16(kgb + koff[1], &k_lds[0][ldsb[1]]);
  gld16(vgb + voff[0], &v_lds[0][ldsb[0]]);
  gld16(vgb + voff[1], &v_lds[0][ldsb[1]]);

  f4 o_acc[2][4] = {};
  float psum[2] = {0.f, 0.f};  // deferred softmax denominator (per-lane partial, per q-subtile)

  // body for one K-tile; CUR is compile-time so all LDS addresses fold to immediates
#define ATTN_BODY(KT, CUR)                                                              \
  {                                                                                     \
    __syncthreads(); /* implicit vmcnt(0): buf[CUR] ready; buf[CUR^1] free */           \
    if ((KT) < 26) {                                                                    \
      const size_t ko = (size_t)((KT) + 1) * 64 * CC;                                   \
      const int vo = ((KT) + 1) * 64;                                                   \
      gld16(kgb + ko + koff[0], &k_lds[(CUR) ^ 1][ldsb[0]]);                            \
      gld16(kgb + ko + koff[1], &k_lds[(CUR) ^ 1][ldsb[1]]);                            \
      gld16(vgb + vo + voff[0], &v_lds[(CUR) ^ 1][ldsb[0]]);                            \
      gld16(vgb + vo + voff[1], &v_lds[(CUR) ^ 1][ldsb[1]]);                            \
    }                                                                                   \
    f4 s_acc[2][4] = {};                                                                \
    _Pragma("unroll")                                                                   \
    for (int nt = 0; nt < 4; ++nt) {                                                    \
      _Pragma("unroll")                                                                 \
      for (int ks = 0; ks < 2; ++ks) {                                                  \
        const int cc = ((ks * 4 + quad) ^ (m & 7)) * 8;                                 \
        const bf8 kf = *(const bf8*)&k_lds[CUR][(nt * 16 + m) * 64 + cc];               \
        s_acc[0][nt] = __builtin_amdgcn_mfma_f32_16x16x32_bf16(kf, qf[0][ks], s_acc[0][nt], 0, 0, 0); \
        s_acc[1][nt] = __builtin_amdgcn_mfma_f32_16x16x32_bf16(kf, qf[1][ks], s_acc[1][nt], 0, 0, 0); \
      }                                                                                 \
    }                                                                                   \
    bf8 pf[2][2];                                                                       \
    _Pragma("unroll")                                                                   \
    for (int sub = 0; sub < 2; ++sub) {                                                 \
      _Pragma("unroll")                                                                 \
      for (int ks = 0; ks < 2; ++ks) {                                                  \
        union { bf8 v; unsigned int w[4]; } pu;                                         \
        _Pragma("unroll")                                                               \
        for (int bb = 0; bb < 2; ++bb) {                                                \
          const int nt = ks * 2 + bb;                                                   \
          const float p0 = fast_exp2(s_acc[sub][nt][0]);                                \
          const float p1 = fast_exp2(s_acc[sub][nt][1]);                                \
          const float p2 = fast_exp2(s_acc[sub][nt][2]);                                \
          const float p3 = fast_exp2(s_acc[sub][nt][3]);                                \
          psum[sub] += (p0 + p1) + (p2 + p3);                                           \
          pu.w[bb * 2 + 0] = (unsigned int)f2bfr(p0) | ((unsigned int)f2bfr(p1) << 16); \
          pu.w[bb * 2 + 1] = (unsigned int)f2bfr(p2) | ((unsigned int)f2bfr(p3) << 16); \
        }                                                                               \
        pf[sub][ks] = pu.v;                                                             \
      }                                                                                 \
    }                                                                                   \
    _Pragma("unroll")                                                                   \
    for (int nt = 0; nt < 4; ++nt) {                                                    \
      _Pragma("unroll")                                                                 \
      for (int ks = 0; ks < 2; ++ks) {                                                  \
        const int cc = ((ks * 4 + quad) ^ (m & 7)) * 8;                                 \
        const bf8 vf = *(const bf8*)&v_lds[CUR][(nt * 16 + m) * 64 + cc];               \
        o_acc[0][nt] = __builtin_amdgcn_mfma_f32_16x16x32_bf16(vf, pf[0][ks], o_acc[0][nt], 0, 0, 0); \
        o_acc[1][nt] = __builtin_amdgcn_mfma_f32_16x16x32_bf16(vf, pf[1][ks], o_acc[1][nt], 0, 0, 0); \
      }                                                                                 \
    }                                                                                   \
  }

  for (int ktp = 0; ktp < 13; ++ktp) {
    const int kt0 = ktp * 2;
    ATTN_BODY(kt0, 0)
    ATTN_BODY(kt0 + 1, 1)
  }
  ATTN_BODY(26, 0)
#undef ATTN_BODY

  // ---- epilogue: denominator = sum over the 4 quads holding q=m, then out += O^T / l ----
  // o_acc[sub][nt][r] = O[q = qt*128+sub*64+wave*16+m][d = nt*16 + quad*4 + r] -> float4 RMW per nt
#pragma unroll
  for (int sub = 0; sub < 2; ++sub) {
    float s = psum[sub];
    s += __shfl_xor(s, 16);
    s += __shfl_xor(s, 32);
    const float inv = 1.0f / s;
    const int rowq = qt * 128 + sub * 64 + wave * 16 + m;
    if (rowq < LL) {
      float* op = out + ((size_t)b * LL + rowq) * CC + h * HD + quad * 4;
#pragma unroll
      for (int nt = 0; nt < 4; ++nt) {
        float4 o4 = *(float4*)&op[nt * 16];
        o4.x += o_acc[sub][nt][0] * inv;
        o4.y += o_acc[sub][nt][1] * inv;
        o4.z += o_acc[sub][nt][2] * inv;
        o4.w += o_acc[sub][nt][3] * inv;
        *(float4*)&op[nt * 16] = o4;
      }
    }
  }
}

extern "C" void kernel_launch(void* const* d_in, const int* in_sizes, int n_in,
                              void* d_out, int out_size, void* d_ws, size_t ws_size,
                              hipStream_t stream) {
  (void)in_sizes; (void)n_in; (void)ws_size; (void)out_size;
  const float* qkv = (const float*)d_in[0];
  const float* lepe_w = (const float*)d_in[1];
  const float* lepe_b = (const float*)d_in[2];
  float* out = (float*)d_out;

  const size_t NE = (size_t)BATCH * LL * CC;
  unsigned short* qb = (unsigned short*)d_ws;
  unsigned short* kb = qb + NE;
  unsigned short* vT = kb + NE;  // 3*NE*2 B ~ 31.9 MB of ws

  combined_kernel<<<dim3(NLEPE + NPREP), 256, 0, stream>>>(qkv, lepe_w, lepe_b, qb, kb, vT, out);
  attn_kernel<<<dim3(14, HEADS, BATCH), 256, 0, stream>>>(qb, kb, vT, out);
}

// Round 3
// 189.488 us; speedup vs baseline: 1.0243x; 1.0102x over previous
//
#include <hip/hip_runtime.h>

#define RR 12
#define LL 1728
#define CC 768
#define HEADS 12
#define HD 64
#define BATCH 4

typedef __attribute__((ext_vector_type(8))) short bf8;   // 8 x bf16
typedef __attribute__((ext_vector_type(4))) float f4;    // 4 x fp32

__device__ inline unsigned short f2bf(float x) {         // RNE-ish
  unsigned int u = __float_as_uint(x);
  return (unsigned short)((u + 0x7FFFu + ((u >> 16) & 1u)) >> 16);
}
__device__ inline unsigned short f2bfr(float x) {        // round-half-up (cheap)
  return (unsigned short)((__float_as_uint(x) + 0x8000u) >> 16);
}

__device__ inline float fast_exp2(float x) {
#if __has_builtin(__builtin_amdgcn_exp2f)
  return __builtin_amdgcn_exp2f(x);
#else
  return exp2f(x);
#endif
}

// async 16B global->LDS (wave-uniform LDS base + lane*16)
__device__ inline void gld16(const unsigned short* g, unsigned short* l) {
  __builtin_amdgcn_global_load_lds((const __attribute__((address_space(1))) unsigned int*)g,
                                   (__attribute__((address_space(3))) unsigned int*)l, 16, 0, 0);
}

#define QSCALE 0.1803368801111244f  /* 0.125 * log2(e): folds softmax base-2 conversion in */

#define NLEPE 5184  /* 432 lines*xgroups x 3 ctiles x 4 batch */
#define NPREP 1296  /* 27 ltiles x 12 heads x 4 batch */

// ---------------- combined prep + lepe (block-uniform partition; 1 launch instead of 3) ------------
// blocks [0, NLEPE): LePE depthwise conv, writes conv+bias into out.
// blocks [NLEPE, NLEPE+NPREP): q,k -> bf16 (q pre-scaled by QSCALE); v -> vT[b][h][d][sigma(k)].
// Slot permutation (for swapped-QK in-register P):
//   sigma(k) with k = nt*16 + quad*4 + r  ->  slot = (nt>>1)*32 + quad*8 + (nt&1)*4 + r
// Applied to BOTH the in-register P fragments (attn) and vT (B-side) -> MFMA K-dim permutation,
// result-invariant. Under this sigma the S^T lane layout of mfma(K,Q) IS the PV B-fragment layout:
// P never touches LDS.
__global__ __launch_bounds__(256) void combined_kernel(const float* __restrict__ qkv,
                                                       const float* __restrict__ w,
                                                       const float* __restrict__ bias,
                                                       unsigned short* __restrict__ qb,
                                                       unsigned short* __restrict__ kb,
                                                       unsigned short* __restrict__ vT,
                                                       float* __restrict__ out) {
  __shared__ __align__(16) unsigned char smem[27648];  // union: lepe w-stage 27 KB / prep tl 8.3 KB
  const int bid = blockIdx.x;
  const int t = threadIdx.x;

  if (bid < NLEPE) {
    // ================= LePE =================
    const int xg = (bid % 3) * 4;            // x0 in {0,4,8}
    const int line = (bid / 3) % 144;        // z*12+y
    const int ct = (bid / 432) % 3;          // c-tile
    const int b = bid / 1296;
    const int z = line / RR;
    const int y = line % RR;
    const int c0 = ct * 256;
    const int c = c0 + t;
    float* w_lds = (float*)smem;

    // coalesced stage of w[c0*27 .. (c0+256)*27) as float4 (6912 floats)
    {
      const float* wsrc = w + (size_t)c0 * 27;
#pragma unroll
      for (int i = 0; i < 7; ++i) {
        const int idx = i * 256 + t;         // float4 index, 0..1727
        if (idx < 1728) *(float4*)&w_lds[idx * 4] = *(const float4*)&wsrc[idx * 4];
      }
    }
    __syncthreads();
    float wreg[27];
#pragma unroll
    for (int j = 0; j < 27; ++j) wreg[j] = w_lds[t * 27 + j];  // stride 27 ⊥ 32: 2-way, free

    const float* vb = qkv + ((size_t)(2 * BATCH + b)) * LL * CC + c;
    const float bv = bias[c];
    float acc[4] = {bv, bv, bv, bv};

#pragma unroll
    for (int dz = -1; dz <= 1; ++dz) {
#pragma unroll
      for (int dy = -1; dy <= 1; ++dy) {
        const int zz = z + dz, yy = y + dy;
        const bool lineok = ((unsigned)zz < RR) & ((unsigned)yy < RR);  // block-uniform
        const int base = (zz * RR + yy) * RR;
        float v6[6];                        // x-positions xg-1 .. xg+4, masked address-safe loads
#pragma unroll
        for (int p = 0; p < 6; ++p) {
          const int xx = xg - 1 + p;
          const bool ok = lineok & ((unsigned)xx < RR);
          const int lp = ok ? base + xx : 0;
          const float vv = vb[(size_t)lp * CC];
          v6[p] = ok ? vv : 0.f;
        }
        const int jb = ((dz + 1) * 3 + (dy + 1)) * 3;
        const float wL = wreg[jb], wC = wreg[jb + 1], wR = wreg[jb + 2];
#pragma unroll
        for (int i = 0; i < 4; ++i)
          acc[i] += wL * v6[i] + wC * v6[i + 1] + wR * v6[i + 2];
      }
    }
    const size_t obase = ((size_t)b * LL + line * RR + xg) * CC + c;
#pragma unroll
    for (int i = 0; i < 4; ++i) out[obase + (size_t)i * CC] = acc[i];

  } else {
    // ================= prep =================
    const int p = bid - NLEPE;
    const int lt = p % 27;
    const int h = (p / 27) % HEADS;
    const int b = p / (27 * HEADS);
    unsigned short* tl = (unsigned short*)smem;  // [d][l_local], stride 65

    // ---- q/k bf16 conversion for rows lt*64.., cols h*64.. ----
    {
      const int r0 = t >> 4;             // 0..15
      const int c4 = (t & 15) * 4;       // 0..60
#pragma unroll
      for (int pi = 0; pi < 4; ++pi) {
        const int row = lt * 64 + pi * 16 + r0;
        const size_t off = ((size_t)b * LL + row) * CC + h * HD + c4;
        const float4 qv = *(const float4*)(qkv + off);
        ushort4 oq;
        oq.x = f2bf(qv.x * QSCALE); oq.y = f2bf(qv.y * QSCALE);
        oq.z = f2bf(qv.z * QSCALE); oq.w = f2bf(qv.w * QSCALE);
        *(ushort4*)(qb + off) = oq;
        const float4 kv = *(const float4*)(qkv + (size_t)BATCH * LL * CC + off);
        ushort4 ok;
        ok.x = f2bf(kv.x); ok.y = f2bf(kv.y); ok.z = f2bf(kv.z); ok.w = f2bf(kv.w);
        *(ushort4*)(kb + off) = ok;
      }
    }

    // ---- vT with slot permutation ----
    const float* vsrc = qkv + ((size_t)(2 * BATCH + b)) * LL * CC;
#pragma unroll
    for (int it = 0; it < 4; ++it) {
      const int idx = it * 256 + t;
      const int lrow = idx >> 4;
      const int c4 = (idx & 15) * 4;
      const float4 vv = *(const float4*)(vsrc + (size_t)(lt * 64 + lrow) * CC + h * HD + c4);
      tl[(c4 + 0) * 65 + lrow] = f2bf(vv.x);
      tl[(c4 + 1) * 65 + lrow] = f2bf(vv.y);
      tl[(c4 + 2) * 65 + lrow] = f2bf(vv.z);
      tl[(c4 + 3) * 65 + lrow] = f2bf(vv.w);
    }
    __syncthreads();
#pragma unroll
    for (int it = 0; it < 4; ++it) {
      const int idx = it * 256 + t;
      const int drow = idx >> 4;
      const int u = idx & 15;            // slot group: s4 = u*4
      const int s4 = u * 4;
      // slots s4..s4+3 hold physical kv rows kbase..kbase+3 (consecutive):
      //   kbase = ((u>>3)*2 + (u&1))*16 + ((u>>1)&3)*4
      const int kbase = (((u >> 3) * 2 + (u & 1)) << 4) + (((u >> 1) & 3) << 2);
      ushort4 o;
      o.x = tl[drow * 65 + kbase + 0];
      o.y = tl[drow * 65 + kbase + 1];
      o.z = tl[drow * 65 + kbase + 2];
      o.w = tl[drow * 65 + kbase + 3];
      *(ushort4*)(vT + (((size_t)(b * HEADS + h) * HD + drow) * LL) + lt * 64 + s4) = o;
    }
  }
}

// ---------------- Flash attention: 3-stage counted-vmcnt pipeline, XCD-affine grid ----------------
// Q=128/block (2 q-subtiles per wave). Swapped QK^T -> in-register P (sigma slots match vT).
// Pipeline: 3 LDS stages (48 KB), prefetch distance 2; per tile: s_waitcnt vmcnt(4) (own tile's
// 4 DMA loads) + raw s_barrier -> next 2 tiles' loads stay IN FLIGHT across the barrier (T3/T4).
// Grid 672 = 8 XCDs x 84: all 14 qt-blocks of one (b,h) pinned to one XCD -> K/V stream hits L2.
__global__ __launch_bounds__(256) void attn_kernel(const unsigned short* __restrict__ qb,
                                                   const unsigned short* __restrict__ kb,
                                                   const unsigned short* __restrict__ vT,
                                                   float* __restrict__ out) {
  __shared__ unsigned short k_lds[3][64 * 64];   // [stage][kv][d], XOR-swizzled chunks (24 KB)
  __shared__ unsigned short v_lds[3][64 * 64];   // [stage][d][slot], XOR-swizzled chunks (24 KB)

  // XCD-affine decode: g&7 = XCD (round-robin dispatch), 84 slots per XCD = 6 (b,h) x 14 qt.
  const int g = blockIdx.x;
  const int xcd = g & 7;
  const int ix = g >> 3;                         // 0..83
  const int qt = ix % 14;                        // 0..13 (qt 13 is a half tile)
  const int bh = xcd * 6 + ix / 14;              // 0..47
  const int h = bh % HEADS;
  const int b = bh / HEADS;

  const int t = threadIdx.x;
  const int lane = t & 63;
  const int wave = t >> 6;
  const int m = lane & 15;
  const int quad = lane >> 4;

  // Q frags (pre-scaled bf16); B-operand layout: lane&15 = q col, quad*8 = d-slice within K=32
  bf8 qf[2][2];
#pragma unroll
  for (int sub = 0; sub < 2; ++sub) {
    int row = qt * 128 + sub * 64 + wave * 16 + m;
    row = row < LL ? row : LL - 1;               // clamp for the qt==13 half tile
    const size_t qbase = ((size_t)(b * LL + row)) * CC + h * HD;
    qf[sub][0] = *(const bf8*)(qb + qbase + quad * 8);
    qf[sub][1] = *(const bf8*)(qb + qbase + 32 + quad * 8);
  }

  // DMA source offsets: chunk cidx=(j*4+wave)*64+lane; row=cidx>>3; src chunk=(cidx&7)^(row&7)
  int koff[2], voff[2], ldsb[2];
#pragma unroll
  for (int j = 0; j < 2; ++j) {
    const int cidx = (j * 4 + wave) * 64 + lane;
    const int row = cidx >> 3;
    const int sc = (cidx & 7) ^ (row & 7);
    koff[j] = row * CC + sc * 8;
    voff[j] = row * LL + sc * 8;
    ldsb[j] = (j * 4 + wave) * 512;
  }

  const unsigned short* kgb = kb + (size_t)b * LL * CC + h * HD;
  const unsigned short* vgb = vT + ((size_t)(b * HEADS + h) * HD) * LL;

#define ISSUE_TILE(KT, BUF)                                                             \
  {                                                                                     \
    const size_t ko = (size_t)(KT) * 64 * CC;                                           \
    const int vo = (KT) * 64;                                                           \
    gld16(kgb + ko + koff[0], &k_lds[BUF][ldsb[0]]);                                    \
    gld16(kgb + ko + koff[1], &k_lds[BUF][ldsb[1]]);                                    \
    gld16(vgb + vo + voff[0], &v_lds[BUF][ldsb[0]]);                                    \
    gld16(vgb + vo + voff[1], &v_lds[BUF][ldsb[1]]);                                    \
  }

  // prologue: tiles 0,1 -> stages 0,1 (8 loads/wave in flight)
  ISSUE_TILE(0, 0)
  ISSUE_TILE(1, 1)

  f4 o_acc[2][4] = {};
  float psum[2] = {0.f, 0.f};  // deferred softmax denominator (per-lane partial, per q-subtile)

  // body: wait own tile's 4 loads (counted!), barrier, prefetch t+2, compute on stage CUR.
  // Barrier doubles as: (a) all waves' tile-KT data landed; (b) all waves done computing KT-1,
  // so stage (CUR+2)%3 = (KT-1)%3 is free for the tile-(KT+2) DMA writes issued after it.
#define ATTN_BODY(KT, CUR, WAITN, DOISSUE)                                              \
  {                                                                                     \
    __asm__ volatile("s_waitcnt vmcnt(" #WAITN ")" ::: "memory");                       \
    __builtin_amdgcn_s_barrier();                                                       \
    if (DOISSUE) ISSUE_TILE((KT) + 2, ((CUR) + 2) % 3)                                  \
    f4 s_acc[2][4] = {};                                                                \
    __builtin_amdgcn_s_setprio(1);                                                      \
    _Pragma("unroll")                                                                   \
    for (int nt = 0; nt < 4; ++nt) {                                                    \
      _Pragma("unroll")                                                                 \
      for (int ks = 0; ks < 2; ++ks) {                                                  \
        const int cc = ((ks * 4 + quad) ^ (m & 7)) * 8;                                 \
        const bf8 kf = *(const bf8*)&k_lds[CUR][(nt * 16 + m) * 64 + cc];               \
        s_acc[0][nt] = __builtin_amdgcn_mfma_f32_16x16x32_bf16(kf, qf[0][ks], s_acc[0][nt], 0, 0, 0); \
        s_acc[1][nt] = __builtin_amdgcn_mfma_f32_16x16x32_bf16(kf, qf[1][ks], s_acc[1][nt], 0, 0, 0); \
      }                                                                                 \
    }                                                                                   \
    __builtin_amdgcn_s_setprio(0);                                                      \
    bf8 pf[2][2];                                                                       \
    _Pragma("unroll")                                                                   \
    for (int sub = 0; sub < 2; ++sub) {                                                 \
      _Pragma("unroll")                                                                 \
      for (int ks = 0; ks < 2; ++ks) {                                                  \
        union { bf8 v; unsigned int w[4]; } pu;                                         \
        _Pragma("unroll")                                                               \
        for (int bb = 0; bb < 2; ++bb) {                                                \
          const int nt = ks * 2 + bb;                                                   \
          const float p0 = fast_exp2(s_acc[sub][nt][0]);                                \
          const float p1 = fast_exp2(s_acc[sub][nt][1]);                                \
          const float p2 = fast_exp2(s_acc[sub][nt][2]);                                \
          const float p3 = fast_exp2(s_acc[sub][nt][3]);                                \
          psum[sub] += (p0 + p1) + (p2 + p3);                                           \
          pu.w[bb * 2 + 0] = (unsigned int)f2bfr(p0) | ((unsigned int)f2bfr(p1) << 16); \
          pu.w[bb * 2 + 1] = (unsigned int)f2bfr(p2) | ((unsigned int)f2bfr(p3) << 16); \
        }                                                                               \
        pf[sub][ks] = pu.v;                                                             \
      }                                                                                 \
    }                                                                                   \
    __builtin_amdgcn_s_setprio(1);                                                      \
    _Pragma("unroll")                                                                   \
    for (int nt = 0; nt < 4; ++nt) {                                                    \
      _Pragma("unroll")                                                                 \
      for (int ks = 0; ks < 2; ++ks) {                                                  \
        const int cc = ((ks * 4 + quad) ^ (m & 7)) * 8;                                 \
        const bf8 vf = *(const bf8*)&v_lds[CUR][(nt * 16 + m) * 64 + cc];               \
        o_acc[0][nt] = __builtin_amdgcn_mfma_f32_16x16x32_bf16(vf, pf[0][ks], o_acc[0][nt], 0, 0, 0); \
        o_acc[1][nt] = __builtin_amdgcn_mfma_f32_16x16x32_bf16(vf, pf[1][ks], o_acc[1][nt], 0, 0, 0); \
      }                                                                                 \
    }                                                                                   \
    __builtin_amdgcn_s_setprio(0);                                                      \
  }

  // tiles 0..23: steady state (issue KT+2 <= 25)
  for (int i = 0; i < 8; ++i) {
    const int t0 = i * 3;
    ATTN_BODY(t0 + 0, 0, 4, true)
    ATTN_BODY(t0 + 1, 1, 4, true)
    ATTN_BODY(t0 + 2, 2, 4, true)
  }
  // tail: tile 24 issues 26; 25/26 no issue; final wait drains.
  ATTN_BODY(24, 0, 4, true)
  ATTN_BODY(25, 1, 4, false)
  ATTN_BODY(26, 2, 0, false)
#undef ATTN_BODY
#undef ISSUE_TILE

  // ---- epilogue: denominator = sum over the 4 quads holding q=m, then out += O^T / l ----
  // o_acc[sub][nt][r] = O[q = qt*128+sub*64+wave*16+m][d = nt*16 + quad*4 + r] -> float4 RMW per nt
#pragma unroll
  for (int sub = 0; sub < 2; ++sub) {
    float s = psum[sub];
    s += __shfl_xor(s, 16);
    s += __shfl_xor(s, 32);
    const float inv = 1.0f / s;
    const int rowq = qt * 128 + sub * 64 + wave * 16 + m;
    if (rowq < LL) {
      float* op = out + ((size_t)b * LL + rowq) * CC + h * HD + quad * 4;
#pragma unroll
      for (int nt = 0; nt < 4; ++nt) {
        float4 o4 = *(float4*)&op[nt * 16];
        o4.x += o_acc[sub][nt][0] * inv;
        o4.y += o_acc[sub][nt][1] * inv;
        o4.z += o_acc[sub][nt][2] * inv;
        o4.w += o_acc[sub][nt][3] * inv;
        *(float4*)&op[nt * 16] = o4;
      }
    }
  }
}

extern "C" void kernel_launch(void* const* d_in, const int* in_sizes, int n_in,
                              void* d_out, int out_size, void* d_ws, size_t ws_size,
                              hipStream_t stream) {
  (void)in_sizes; (void)n_in; (void)ws_size; (void)out_size;
  const float* qkv = (const float*)d_in[0];
  const float* lepe_w = (const float*)d_in[1];
  const float* lepe_b = (const float*)d_in[2];
  float* out = (float*)d_out;

  const size_t NE = (size_t)BATCH * LL * CC;
  unsigned short* qb = (unsigned short*)d_ws;
  unsigned short* kb = qb + NE;
  unsigned short* vT = kb + NE;  // 3*NE*2 B ~ 31.9 MB of ws

  combined_kernel<<<dim3(NLEPE + NPREP), 256, 0, stream>>>(qkv, lepe_w, lepe_b, qb, kb, vT, out);
  attn_kernel<<<dim3(672), 256, 0, stream>>>(qb, kb, vT, out);
}

// Round 5
// 181.085 us; speedup vs baseline: 1.0718x; 1.0464x over previous
//
#include <hip/hip_runtime.h>

#define RR 12
#define LL 1728
#define CC 768
#define HEADS 12
#define HD 64
#define BATCH 4

typedef __attribute__((ext_vector_type(8))) short bf8;   // 8 x bf16
typedef __attribute__((ext_vector_type(4))) float f4;    // 4 x fp32

__device__ inline unsigned short f2bf(float x) {         // RNE-ish
  unsigned int u = __float_as_uint(x);
  return (unsigned short)((u + 0x7FFFu + ((u >> 16) & 1u)) >> 16);
}
__device__ inline unsigned short f2bfr(float x) {        // round-half-up (cheap)
  return (unsigned short)((__float_as_uint(x) + 0x8000u) >> 16);
}

__device__ inline float fast_exp2(float x) {
#if __has_builtin(__builtin_amdgcn_exp2f)
  return __builtin_amdgcn_exp2f(x);
#else
  return exp2f(x);
#endif
}

// async 16B global->LDS (wave-uniform LDS base + lane*16)
__device__ inline void gld16(const unsigned short* g, unsigned short* l) {
  __builtin_amdgcn_global_load_lds((const __attribute__((address_space(1))) unsigned int*)g,
                                   (__attribute__((address_space(3))) unsigned int*)l, 16, 0, 0);
}

#define QSCALE 0.1803368801111244f  /* 0.125 * log2(e): folds softmax base-2 conversion in */

#define NLEPE 1728  /* 144 lines x 3 ctiles x 4 batch (full line of 12 x per block) */
#define NPREP 1296  /* 27 ltiles x 12 heads x 4 batch */

// ---------------- combined prep + lepe (block-uniform partition; 1 launch instead of 3) ------------
// blocks [0, NLEPE): LePE depthwise conv, FULL 12-x line per block (w-stage amortized 3x vs before),
//                    writes conv+bias into out.
// blocks [NLEPE, NLEPE+NPREP): q,k -> bf16 (q pre-scaled by QSCALE); v -> vT[b][h][d][sigma(k)].
// Slot permutation (for swapped-QK in-register P):
//   sigma(k) with k = nt*16 + quad*4 + r  ->  slot = (nt>>1)*32 + quad*8 + (nt&1)*4 + r
// Applied to BOTH the in-register P fragments (attn) and vT (B-side) -> MFMA K-dim permutation,
// result-invariant. Under this sigma the S^T lane layout of mfma(K,Q) IS the PV B-fragment layout:
// P never touches LDS.
__global__ __launch_bounds__(256) void combined_kernel(const float* __restrict__ qkv,
                                                       const float* __restrict__ w,
                                                       const float* __restrict__ bias,
                                                       unsigned short* __restrict__ qb,
                                                       unsigned short* __restrict__ kb,
                                                       unsigned short* __restrict__ vT,
                                                       float* __restrict__ out) {
  __shared__ __align__(16) unsigned char smem[27648];  // union: lepe w-stage 27 KB / prep tl 8.3 KB
  const int bid = blockIdx.x;
  const int t = threadIdx.x;

  if (bid < NLEPE) {
    // ================= LePE (full line: 12 x-positions) =================
    const int line = bid % 144;              // z*12+y
    const int ct = (bid / 144) % 3;          // c-tile
    const int b = bid / 432;
    const int z = line / RR;
    const int y = line % RR;
    const int c0 = ct * 256;
    const int c = c0 + t;
    float* w_lds = (float*)smem;

    // coalesced stage of w[c0*27 .. (c0+256)*27) as float4 (6912 floats)
    {
      const float* wsrc = w + (size_t)c0 * 27;
#pragma unroll
      for (int i = 0; i < 7; ++i) {
        const int idx = i * 256 + t;         // float4 index, 0..1727
        if (idx < 1728) *(float4*)&w_lds[idx * 4] = *(const float4*)&wsrc[idx * 4];
      }
    }
    __syncthreads();
    float wreg[27];
#pragma unroll
    for (int j = 0; j < 27; ++j) wreg[j] = w_lds[t * 27 + j];  // stride 27 ⊥ 32: 2-way, free

    const float* vb = qkv + ((size_t)(2 * BATCH + b)) * LL * CC + c;
    const float bv = bias[c];
    float acc[RR];
#pragma unroll
    for (int i = 0; i < RR; ++i) acc[i] = bv;

#pragma unroll
    for (int dz = -1; dz <= 1; ++dz) {
#pragma unroll
      for (int dy = -1; dy <= 1; ++dy) {
        const int zz = z + dz, yy = y + dy;
        const bool lineok = ((unsigned)zz < RR) & ((unsigned)yy < RR);  // block-uniform
        const int base = (zz * RR + yy) * RR;
        float v14[RR + 2];                  // x-positions -1 .. 12, masked address-safe loads
#pragma unroll
        for (int p = 0; p < RR + 2; ++p) {
          const int xx = p - 1;
          const bool ok = lineok & ((unsigned)xx < RR);
          const int lp = ok ? base + xx : 0;
          const float vv = vb[(size_t)lp * CC];
          v14[p] = ok ? vv : 0.f;
        }
        const int jb = ((dz + 1) * 3 + (dy + 1)) * 3;
        const float wL = wreg[jb], wC = wreg[jb + 1], wR = wreg[jb + 2];
#pragma unroll
        for (int i = 0; i < RR; ++i)
          acc[i] += wL * v14[i] + wC * v14[i + 1] + wR * v14[i + 2];
      }
    }
    const size_t obase = ((size_t)b * LL + line * RR) * CC + c;
#pragma unroll
    for (int i = 0; i < RR; ++i) out[obase + (size_t)i * CC] = acc[i];

  } else {
    // ================= prep =================
    const int p = bid - NLEPE;
    const int lt = p % 27;
    const int h = (p / 27) % HEADS;
    const int b = p / (27 * HEADS);
    unsigned short* tl = (unsigned short*)smem;  // [d][l_local], stride 65

    // ---- q/k bf16 conversion for rows lt*64.., cols h*64.. ----
    {
      const int r0 = t >> 4;             // 0..15
      const int c4 = (t & 15) * 4;       // 0..60
#pragma unroll
      for (int pi = 0; pi < 4; ++pi) {
        const int row = lt * 64 + pi * 16 + r0;
        const size_t off = ((size_t)b * LL + row) * CC + h * HD + c4;
        const float4 qv = *(const float4*)(qkv + off);
        ushort4 oq;
        oq.x = f2bf(qv.x * QSCALE); oq.y = f2bf(qv.y * QSCALE);
        oq.z = f2bf(qv.z * QSCALE); oq.w = f2bf(qv.w * QSCALE);
        *(ushort4*)(qb + off) = oq;
        const float4 kv = *(const float4*)(qkv + (size_t)BATCH * LL * CC + off);
        ushort4 ok;
        ok.x = f2bf(kv.x); ok.y = f2bf(kv.y); ok.z = f2bf(kv.z); ok.w = f2bf(kv.w);
        *(ushort4*)(kb + off) = ok;
      }
    }

    // ---- vT with slot permutation ----
    const float* vsrc = qkv + ((size_t)(2 * BATCH + b)) * LL * CC;
#pragma unroll
    for (int it = 0; it < 4; ++it) {
      const int idx = it * 256 + t;
      const int lrow = idx >> 4;
      const int c4 = (idx & 15) * 4;
      const float4 vv = *(const float4*)(vsrc + (size_t)(lt * 64 + lrow) * CC + h * HD + c4);
      tl[(c4 + 0) * 65 + lrow] = f2bf(vv.x);
      tl[(c4 + 1) * 65 + lrow] = f2bf(vv.y);
      tl[(c4 + 2) * 65 + lrow] = f2bf(vv.z);
      tl[(c4 + 3) * 65 + lrow] = f2bf(vv.w);
    }
    __syncthreads();
#pragma unroll
    for (int it = 0; it < 4; ++it) {
      const int idx = it * 256 + t;
      const int drow = idx >> 4;
      const int u = idx & 15;            // slot group: s4 = u*4
      const int s4 = u * 4;
      // slots s4..s4+3 hold physical kv rows kbase..kbase+3 (consecutive):
      //   kbase = ((u>>3)*2 + (u&1))*16 + ((u>>1)&3)*4
      const int kbase = (((u >> 3) * 2 + (u & 1)) << 4) + (((u >> 1) & 3) << 2);
      ushort4 o;
      o.x = tl[drow * 65 + kbase + 0];
      o.y = tl[drow * 65 + kbase + 1];
      o.z = tl[drow * 65 + kbase + 2];
      o.w = tl[drow * 65 + kbase + 3];
      *(ushort4*)(vT + (((size_t)(b * HEADS + h) * HD + drow) * LL) + lt * 64 + s4) = o;
    }
  }
}

// ---------------- Flash attention: Q=128/block as 8 waves x 16 q-rows, one residency round -------
// 512-thread blocks, 3-stage LDS (48 KB), __launch_bounds__(512,6) caps VGPR at 85 -> 3 blocks/CU
// (24 waves/CU) -> all 672 blocks resident in ONE round (vs 2 rounds in R1-R3: kernel ~ rounds x
// T_block). Per-wave body is the lean 16-row body. Counted s_waitcnt vmcnt(2) BEFORE s_barrier
// (R3-proven order; R4's barrier-first was a race): all waves' tile-i DMA landed at barrier exit,
// next tile's 2 loads stay in flight. KV-stagger (start tile (qt*2)%27) + XCD-affine grid kept.
__global__ __launch_bounds__(512, 6) void attn_kernel(const unsigned short* __restrict__ qb,
                                                      const unsigned short* __restrict__ kb,
                                                      const unsigned short* __restrict__ vT,
                                                      float* __restrict__ out) {
  __shared__ unsigned short k_lds[3][64 * 64];   // [stage][kv][d], XOR-swizzled chunks (24 KB)
  __shared__ unsigned short v_lds[3][64 * 64];   // [stage][d][slot], XOR-swizzled chunks (24 KB)

  // XCD-affine decode: g&7 = XCD (round-robin dispatch), 84 slots per XCD = 6 bh x 14 qt.
  const int g = blockIdx.x;
  const int xcd = g & 7;
  const int ix = g >> 3;                         // 0..83
  const int qt = ix % 14;                        // 0..13 (qt 13 is a half tile)
  const int bh = xcd * 6 + ix / 14;              // 0..47
  const int h = bh % HEADS;
  const int b = bh / HEADS;
  const int stg = (qt * 2) % 27;                 // KV start tile (stagger)

  const int t = threadIdx.x;
  const int lane = t & 63;
  const int wave = t >> 6;                       // 0..7
  const int m = lane & 15;
  const int quad = lane >> 4;

  // Q frags (pre-scaled bf16); B-operand layout: lane&15 = q col, quad*8 = d-slice within K=32
  bf8 qf[2];
  {
    int row = qt * 128 + wave * 16 + m;
    row = row < LL ? row : LL - 1;               // clamp for the qt==13 half tile (waves 4-7)
    const size_t qbase = ((size_t)(b * LL + row)) * CC + h * HD;
    qf[0] = *(const bf8*)(qb + qbase + quad * 8);
    qf[1] = *(const bf8*)(qb + qbase + 32 + quad * 8);
  }

  // DMA source offsets: chunk cidx = wave*64+lane (512 chunks = one 8KB matrix);
  // row = cidx>>3; src chunk = (cidx&7)^(row&7)  (XOR swizzle, read side matches)
  int koff, voff, ldsb;
  {
    const int cidx = wave * 64 + lane;
    const int row = cidx >> 3;
    const int sc = (cidx & 7) ^ (row & 7);
    koff = row * CC + sc * 8;
    voff = row * LL + sc * 8;
    ldsb = wave * 512;
  }

  const unsigned short* kgb = kb + (size_t)b * LL * CC + h * HD;
  const unsigned short* vgb = vT + ((size_t)(b * HEADS + h) * HD) * LL;

#define ISSUE_TILE(KT, BUF)                                                             \
  {                                                                                     \
    gld16(kgb + (size_t)(KT) * (64 * CC) + koff, &k_lds[BUF][ldsb]);                    \
    gld16(vgb + (KT) * 64 + voff, &v_lds[BUF][ldsb]);                                   \
  }

  // prologue: tiles stg, stg+1 -> stages 0,1 (4 loads/wave in flight)
  ISSUE_TILE(stg, 0)
  {
    int k1 = stg + 1; if (k1 >= 27) k1 -= 27;
    ISSUE_TILE(k1, 1)
  }

  f4 o_acc[4] = {};
  float psum = 0.f;   // deferred softmax denominator (per-lane partial over its 16 slots/tile)

  // body i: physical tile (stg+i)%27 on stage i%3.
  // vmcnt(2): own tile-i loads landed (tile i+1's 2 stay in flight); barrier: ALL waves' tile-i
  // loads landed AND stage (i+2)%3 (read in body i-1) is free; then issue tile i+2 into it.
#define ATTN_BODY(I, STG, WAITN, DOISSUE)                                               \
  {                                                                                     \
    __asm__ volatile("s_waitcnt vmcnt(" #WAITN ")" ::: "memory");                       \
    __builtin_amdgcn_s_barrier();                                                       \
    if (DOISSUE) {                                                                      \
      int ktn = stg + (I) + 2; if (ktn >= 27) ktn -= 27;                                \
      ISSUE_TILE(ktn, ((STG) + 2) % 3)                                                  \
    }                                                                                   \
    f4 s_acc[4] = {};                                                                   \
    __builtin_amdgcn_s_setprio(1);                                                      \
    _Pragma("unroll")                                                                   \
    for (int nt = 0; nt < 4; ++nt) {                                                    \
      _Pragma("unroll")                                                                 \
      for (int ks = 0; ks < 2; ++ks) {                                                  \
        const int cc = ((ks * 4 + quad) ^ (m & 7)) * 8;                                 \
        const bf8 kf = *(const bf8*)&k_lds[STG][(nt * 16 + m) * 64 + cc];               \
        s_acc[nt] = __builtin_amdgcn_mfma_f32_16x16x32_bf16(kf, qf[ks], s_acc[nt], 0, 0, 0); \
      }                                                                                 \
    }                                                                                   \
    __builtin_amdgcn_s_setprio(0);                                                      \
    bf8 pf[2];                                                                          \
    _Pragma("unroll")                                                                   \
    for (int ks = 0; ks < 2; ++ks) {                                                    \
      union { bf8 v; unsigned int w[4]; } pu;                                           \
      _Pragma("unroll")                                                                 \
      for (int bb = 0; bb < 2; ++bb) {                                                  \
        const int nt = ks * 2 + bb;                                                     \
        const float p0 = fast_exp2(s_acc[nt][0]);                                       \
        const float p1 = fast_exp2(s_acc[nt][1]);                                       \
        const float p2 = fast_exp2(s_acc[nt][2]);                                       \
        const float p3 = fast_exp2(s_acc[nt][3]);                                       \
        psum += (p0 + p1) + (p2 + p3);                                                  \
        pu.w[bb * 2 + 0] = (unsigned int)f2bfr(p0) | ((unsigned int)f2bfr(p1) << 16);   \
        pu.w[bb * 2 + 1] = (unsigned int)f2bfr(p2) | ((unsigned int)f2bfr(p3) << 16);   \
      }                                                                                 \
      pf[ks] = pu.v;                                                                    \
    }                                                                                   \
    __builtin_amdgcn_s_setprio(1);                                                      \
    _Pragma("unroll")                                                                   \
    for (int nt = 0; nt < 4; ++nt) {                                                    \
      _Pragma("unroll")                                                                 \
      for (int ks = 0; ks < 2; ++ks) {                                                  \
        const int cc = ((ks * 4 + quad) ^ (m & 7)) * 8;                                 \
        const bf8 vf = *(const bf8*)&v_lds[STG][(nt * 16 + m) * 64 + cc];               \
        o_acc[nt] = __builtin_amdgcn_mfma_f32_16x16x32_bf16(vf, pf[ks], o_acc[nt], 0, 0, 0); \
      }                                                                                 \
    }                                                                                   \
    __builtin_amdgcn_s_setprio(0);                                                      \
  }

  // bodies 0..23 (always issue i+2 <= 25), then peeled 24 (issues 26), 25, 26 (drain).
  for (int ip = 0; ip < 8; ++ip) {
    const int i0 = ip * 3;
    ATTN_BODY(i0 + 0, 0, 2, true)
    ATTN_BODY(i0 + 1, 1, 2, true)
    ATTN_BODY(i0 + 2, 2, 2, true)
  }
  ATTN_BODY(24, 0, 2, true)
  ATTN_BODY(25, 1, 2, false)
  ATTN_BODY(26, 2, 0, false)
#undef ATTN_BODY
#undef ISSUE_TILE

  // ---- epilogue: denominator = sum over the 4 quads holding q=m, then out += O^T / l ----
  // o_acc[nt][r] = O[q = qt*128+wave*16+m][d = nt*16 + quad*4 + r]  -> float4 RMW per nt
  float s = psum;
  s += __shfl_xor(s, 16);
  s += __shfl_xor(s, 32);
  const float inv = 1.0f / s;
  const int rowq = qt * 128 + wave * 16 + m;
  if (rowq < LL) {
    float* op = out + ((size_t)b * LL + rowq) * CC + h * HD + quad * 4;
#pragma unroll
    for (int nt = 0; nt < 4; ++nt) {
      float4 o4 = *(float4*)&op[nt * 16];
      o4.x += o_acc[nt][0] * inv;
      o4.y += o_acc[nt][1] * inv;
      o4.z += o_acc[nt][2] * inv;
      o4.w += o_acc[nt][3] * inv;
      *(float4*)&op[nt * 16] = o4;
    }
  }
}

extern "C" void kernel_launch(void* const* d_in, const int* in_sizes, int n_in,
                              void* d_out, int out_size, void* d_ws, size_t ws_size,
                              hipStream_t stream) {
  (void)in_sizes; (void)n_in; (void)ws_size; (void)out_size;
  const float* qkv = (const float*)d_in[0];
  const float* lepe_w = (const float*)d_in[1];
  const float* lepe_b = (const float*)d_in[2];
  float* out = (float*)d_out;

  const size_t NE = (size_t)BATCH * LL * CC;
  unsigned short* qb = (unsigned short*)d_ws;
  unsigned short* kb = qb + NE;
  unsigned short* vT = kb + NE;  // 3*NE*2 B ~ 31.9 MB of ws

  combined_kernel<<<dim3(NLEPE + NPREP), 256, 0, stream>>>(qkv, lepe_w, lepe_b, qb, kb, vT, out);
  attn_kernel<<<dim3(672), 512, 0, stream>>>(qb, kb, vT, out);
}